// Round 12
// baseline (168.872 us; speedup 1.0000x reference)
//
#include <hip/hip_runtime.h>

// ROSA 1-bit, B=4, T=2048, C=128 (512 sequences).
// Round 12: round-11 packed-domain epilogue with the entry-key bug fixed:
// rp must include the current itc field (round 11 dropped it -> carry-in
// runs decoded with wrong d -> negative e1p -> OOB sbits read -> abort).
// Key = (run<<6)|(itc<<3)|(7-g); cross-stream max directly on u16 pairs
// (16 regs x 3 shfl_xor + pk_max), expand once (4 values/lane).
// Saturating step add; run>=1008 (legit or saturated) -> ballot-gated exact
// scalar fallback (round-6 path), so caps never corrupt results.

#define TT 2048
#define CC 128
#define NW 64
#define NSEQ 512
#define SBITS_WORDS (NSEQ * NW)       // 128 KB
#define RES_WORDS (NSEQ * TT)         // 4 MB, layout [q][i]

typedef short          s16x2 __attribute__((ext_vector_type(2)));
typedef unsigned short u16x2 __attribute__((ext_vector_type(2)));

__device__ __forceinline__ unsigned pk_sign(unsigned x) {   // per-half sign mask
    s16x2 v = __builtin_bit_cast(s16x2, x);
    v = v >> 15;
    return __builtin_bit_cast(unsigned, v);
}
__device__ __forceinline__ unsigned pk_shl1(unsigned x) {
    u16x2 v = __builtin_bit_cast(u16x2, x);
    v = v << 1;
    return __builtin_bit_cast(unsigned, v);
}
__device__ __forceinline__ unsigned pk_addsat64(unsigned x) {
    u16x2 v = __builtin_bit_cast(u16x2, x);
    u16x2 c = {64, 64};
    v = __builtin_elementwise_add_sat(v, c);
    return __builtin_bit_cast(unsigned, v);
}
__device__ __forceinline__ unsigned pk_maxu(unsigned a, unsigned b) {
    u16x2 x = __builtin_bit_cast(u16x2, a);
    u16x2 y = __builtin_bit_cast(u16x2, b);
    u16x2 r = __builtin_elementwise_max(x, y);
    return __builtin_bit_cast(unsigned, r);
}

// ---------------- kernel 0: pack bits ----------------
__global__ void k_bits(const float* __restrict__ x, unsigned* __restrict__ sbits)
{
    const int b = blockIdx.x >> 6;
    const int w = blockIdx.x & 63;
    const int t = threadIdx.x;
    __shared__ unsigned char sbyt[32 * 132];

    #pragma unroll
    for (int r = 0; r < 16; ++r) {
        const int e  = t + (r << 8);
        const int ii = e >> 7;
        const int c  = e & 127;
        const float v = x[((size_t)(b * TT + (w << 5) + ii)) * CC + c];
        sbyt[ii * 132 + c] = (v > 0.0f) ? 1u : 0u;
    }
    __syncthreads();

    if (t < CC) {
        unsigned word = 0u;
        #pragma unroll
        for (int ii = 0; ii < 32; ++ii)
            word |= (unsigned)(sbyt[ii * 132 + t] & 1u) << ii;
        sbits[((b << 7) | t) * NW + w] = word;
    }
}

// ---------------- kernel 1: tiled diagonal DP (packed keys) ----------------
__global__ __launch_bounds__(256, 4) void k_dp2(
    const unsigned* __restrict__ sbits, unsigned* __restrict__ res)
{
    const int u = blockIdx.x;            // 0..35 (triangular (k, chunk))
    const int q = blockIdx.y;            // sequence = b*128 + c
    int k = 0;
    #pragma unroll
    for (int kk = 1; kk < 8; ++kk) if (u >= (kk * (kk + 1)) / 2) k = kk;
    const int chunk = u - (k * (k + 1)) / 2;
    const int D0 = 1 + (chunk << 8);

    const int tid  = threadIdx.x;
    const int lane = tid & 63;
    const int wv   = tid >> 6;
    const int g    = lane >> 3;          // stream in wave
    const int lm   = lane & 7;           // lane within stream
    const int wB   = k << 3;
    const int wloc = wB + lm;            // fixed output word of this lane
    const int kb   = k << 8;

    __shared__ unsigned pad[128];        // [0..63]=0, [64+w]=word w
    __shared__ unsigned seedl[256];      // incoming run at tile base per diagonal
    __shared__ unsigned wres[4][8][33];

    if (tid < 64) pad[tid] = 0u;
    else if (tid < 128) pad[tid] = sbits[q * NW + (tid - 64)];
    __syncthreads();

    // --- seed precompute: thread t -> diagonal D0+t ---
    {
        const int d = D0 + tid;
        unsigned acc = 0u;
        if (d < kb) {
            const int dw = d >> 5, dr = d & 31;
            for (int w = wB - 1; w >= 0; --w) {
                const int sw = w - dw;
                const unsigned u0 = pad[64 + sw];
                const unsigned u1 = pad[63 + sw];
                const unsigned shw = dr ? ((u0 << dr) | (u1 >> (32 - dr))) : u0;
                const unsigned ew = (sw > 0) ? 0xFFFFFFFFu
                                  : ((sw == 0) ? (0xFFFFFFFFu << dr) : 0u);
                const unsigned mw = (~(pad[64 + w] ^ shw)) & ew;
                const unsigned t2 = (mw == 0xFFFFFFFFu) ? 32u
                                  : (unsigned)__builtin_clz(~mw);
                acc += t2;
                if (t2 < 32u) break;
            }
        }
        seedl[tid] = acc;
    }
    __syncthreads();

    const unsigned a = pad[64 + wloc];

    unsigned lmaxp[16];
    #pragma unroll
    for (int j = 0; j < 16; ++j) lmaxp[j] = 0u;

    unsigned incs[8];                    // exact incoming runs (for fallback)

    #pragma unroll
    for (int it = 0; it < 8; ++it) {
        const int d  = D0 + (it << 5) + (wv << 3) + g;
        const int dw = d >> 5;
        const int dr = d & 31;

        const int s = wloc - dw;
        const unsigned b0 = pad[64 + s];
        const unsigned b1 = pad[63 + s];
        const unsigned sh = dr ? ((b0 << dr) | (b1 >> (32 - dr))) : b0;
        const unsigned em = (s > 0) ? 0xFFFFFFFFu
                          : ((s == 0) ? (0xFFFFFFFFu << dr) : 0u);
        const unsigned m = (~(a ^ sh)) & em;

        // --- incoming run: seed for stream heads, clz fast path otherwise ---
        const unsigned seedv = seedl[(it << 5) + (wv << 3) + g];
        const unsigned pm = (unsigned)__shfl_up((int)m, 1, 64);
        const unsigned lead = (unsigned)__builtin_clz(~pm | 1u);
        unsigned inc = (lm == 0) ? seedv : lead;

        // exact rare fallback: some lane's previous word fully matched
        if (__builtin_expect(
                __ballot((lm > 0) && (pm == 0xFFFFFFFFu)) != 0ULL, 0)) {
            if ((lm > 0) && (pm == 0xFFFFFFFFu)) {
                unsigned acc = 0u;
                int w;
                for (w = wloc - 1; w >= wB; --w) {
                    const int sw = w - dw;
                    const unsigned u0 = pad[64 + sw];
                    const unsigned u1 = pad[63 + sw];
                    const unsigned shw = dr ? ((u0 << dr) | (u1 >> (32 - dr))) : u0;
                    const unsigned ew = (sw > 0) ? 0xFFFFFFFFu
                                      : ((sw == 0) ? (0xFFFFFFFFu << dr) : 0u);
                    const unsigned mw = (~(pad[64 + w] ^ shw)) & ew;
                    const unsigned t2 = (mw == 0xFFFFFFFFu) ? 32u
                                      : (unsigned)__builtin_clz(~mw);
                    acc += t2;
                    if (t2 < 32u) break;
                }
                if (w < wB) acc += seedv;
                inc = acc;
            }
        }
        incs[it] = inc;

        // --- chain-B (bits 16..31) entry: run into bit 16, capped clz ---
        const unsigned nm   = ~m;
        const unsigned u16c = (unsigned)__builtin_clz((nm << 16) | 0x8000u);
        const unsigned s16  = u16c + ((u16c == 16u) ? inc : 0u);

        const unsigned itcv = (unsigned)((7 - it) << 3) * 0x10001u;
        const unsigned ci = inc > 1023u ? 1023u : inc;
        const unsigned cs = s16 > 1023u ? 1023u : s16;
        unsigned rp = (ci << 6) | (cs << 22) | itcv;   // FIX: carry itc field

        const unsigned mr  = __builtin_bitreverse32(m);
        unsigned mmr = (mr >> 16) | (mr << 16);

        #pragma unroll
        for (int j = 0; j < 16; ++j) {
            const unsigned sm = pk_sign(mmr);        // v_pk_ashrrev_i16
            mmr = pk_shl1(mmr);                      // v_pk_lshlrev_b16
            rp  = pk_addsat64(rp);                   // v_pk_add_u16 clamp
            rp  = (rp & sm) | (itcv & ~sm);          // v_bfi_b32
            lmaxp[j] = pk_maxu(lmaxp[j], rp);        // v_pk_max_u16
        }
    }

    // --- embed stream id (constant per lane) into spare low bits ---
    const unsigned gk2 = (unsigned)(7 - g) * 0x10001u;
    #pragma unroll
    for (int j = 0; j < 16; ++j) lmaxp[j] |= gk2;

    // --- packed cross-stream reduce (lanes lm, lm+8, ..., lm+56) ---
    #pragma unroll
    for (int j = 0; j < 16; ++j) {
        unsigned v = lmaxp[j];
        v = pk_maxu(v, (unsigned)__shfl_xor((int)v, 8, 64));
        v = pk_maxu(v, (unsigned)__shfl_xor((int)v, 16, 64));
        v = pk_maxu(v, (unsigned)__shfl_xor((int)v, 32, 64));
        lmaxp[j] = v;
    }

    // --- overflow / saturation detect: any run field >= 1008 ---
    unsigned mx = lmaxp[0];
    #pragma unroll
    for (int j = 1; j < 16; ++j) mx = pk_maxu(mx, lmaxp[j]);
    const bool ovf = ((mx & 0x0000FC00u) == 0x0000FC00u) ||
                     ((mx & 0xFC000000u) == 0xFC000000u);

    if (__builtin_expect(__ballot(ovf) == 0ULL, 1)) {
        // --- fast epilogue: expand 4 values per lane, write wres ---
        const unsigned Kw = 2048u - (unsigned)D0 - (unsigned)(wv << 3) - 231u;
        #pragma unroll
        for (int e = 0; e < 4; ++e) {
            const int j = ((g & 3) << 2) + e;
            const unsigned r32 = lmaxp[j];
            const unsigned h = (g >= 4) ? (r32 >> 16) : (r32 & 0xFFFFu);
            const unsigned v = ((h >> 6) << 11) + ((h & 0x38u) << 2) + (h & 7u) + Kw;
            wres[wv][lm][(g << 2) + e] = v;
        }
    } else {
        // --- exact fallback (rare): full 32-bit recompute, round-6 path ---
        unsigned lm32[32];
        #pragma unroll
        for (int bb = 0; bb < 32; ++bb) lm32[bb] = 0u;
        for (int it = 0; it < 8; ++it) {
            const int d  = D0 + (it << 5) + (wv << 3) + g;
            const int dw = d >> 5;
            const int dr = d & 31;
            const unsigned dcode = (unsigned)(TT - d) & 2047u;
            const int s = wloc - dw;
            const unsigned b0 = pad[64 + s];
            const unsigned b1 = pad[63 + s];
            const unsigned sh = dr ? ((b0 << dr) | (b1 >> (32 - dr))) : b0;
            const unsigned em = (s > 0) ? 0xFFFFFFFFu
                              : ((s == 0) ? (0xFFFFFFFFu << dr) : 0u);
            const unsigned m = (~(a ^ sh)) & em;
            unsigned pkv = (incs[it] << 11) | dcode;
            for (int bb = 0; bb < 32; ++bb) {
                pkv = ((m >> bb) & 1u) ? (pkv + 0x800u) : dcode;
                lm32[bb] = lm32[bb] >= pkv ? lm32[bb] : pkv;
            }
        }
        #pragma unroll
        for (int bb = 0; bb < 32; ++bb) {
            unsigned v = lm32[bb];
            v = max(v, (unsigned)__shfl_xor((int)v, 8, 64));
            v = max(v, (unsigned)__shfl_xor((int)v, 16, 64));
            v = max(v, (unsigned)__shfl_xor((int)v, 32, 64));
            lm32[bb] = v;
        }
        if (g == 0) {
            #pragma unroll
            for (int bb = 0; bb < 32; ++bb) wres[wv][lm][bb] = lm32[bb];
        }
    }
    __syncthreads();

    // --- block merge + contiguous atomics into res[q][i] ---
    {
        const int lw = tid >> 5, bb = tid & 31;
        const unsigned v = max(max(wres[0][lw][bb], wres[1][lw][bb]),
                               max(wres[2][lw][bb], wres[3][lw][bb]));
        if (v >> 11) {
            const int i = ((wB + lw) << 5) + bb;
            atomicMax(&res[(size_t)q * TT + i], v);
        }
    }
}

// ---------------- kernel 2: decode (LDS transpose) ----------------
__global__ void k_dec(const unsigned* __restrict__ sbits,
                      const unsigned* __restrict__ res,
                      const float* __restrict__ emb0,
                      const float* __restrict__ emb1,
                      float* __restrict__ out)
{
    const int b  = blockIdx.y;
    const int i0 = blockIdx.x << 4;
    const int t  = threadIdx.x;
    __shared__ float trans[16][CC + 4];

    const int c  = t >> 1;
    const int q8 = (t & 1) << 3;
    const unsigned* rp = res + ((size_t)((b << 7) | c) * TT) + i0 + q8;
    const unsigned* bw = sbits + ((size_t)((b << 7) | c)) * NW;
    const float e0 = emb0[c], e1 = emb1[c];

    #pragma unroll
    for (int jj = 0; jj < 8; ++jj) {
        const unsigned v = rp[jj];
        const int i = i0 + q8 + jj;
        float val = 0.0f;
        if (v >> 11) {
            const int d   = TT - (int)(v & 2047u);
            const int e1p = i - d + 1;
            val = ((bw[e1p >> 5] >> (e1p & 31)) & 1u) ? e1 : e0;
        }
        trans[q8 + jj][c] = val;
    }
    __syncthreads();

    const int ii = t >> 4;
    const int c0 = (t & 15) << 3;
    float4 w0 = *(const float4*)&trans[ii][c0];
    float4 w1 = *(const float4*)&trans[ii][c0 + 4];
    float* op = out + ((size_t)(b * TT + i0 + ii)) * CC + c0;
    *(float4*)op       = w0;
    *(float4*)(op + 4) = w1;
}

extern "C" void kernel_launch(void* const* d_in, const int* in_sizes, int n_in,
                              void* d_out, int out_size, void* d_ws, size_t ws_size,
                              hipStream_t stream)
{
    const float* x    = (const float*)d_in[0];
    const float* emb0 = (const float*)d_in[1];
    const float* emb1 = (const float*)d_in[2];
    float* out        = (float*)d_out;

    unsigned* sbits = (unsigned*)d_ws;                    // 128 KB
    unsigned* res   = (unsigned*)d_ws + SBITS_WORDS;      // 4 MB

    hipMemsetAsync((void*)res, 0, (size_t)RES_WORDS * 4, stream);
    k_bits<<<dim3(4 * 64), dim3(256), 0, stream>>>(x, sbits);
    k_dp2<<<dim3(36, NSEQ), dim3(256), 0, stream>>>(sbits, res);
    k_dec<<<dim3(TT / 16, 4), dim3(256), 0, stream>>>(sbits, res, emb0, emb1, out);
}

// Round 13
// 160.382 us; speedup vs baseline: 1.0529x; 1.0529x over previous
//
#include <hip/hip_runtime.h>

// ROSA 1-bit, B=4, T=2048, C=128 (512 sequences).
// Round 13: 16 diagonals-iterations per block (was 8) -> grid 36->20 blocks
// per sequence; pad-load/sync/epilogue/merge/atomics amortize over 2x cells.
// Time model (m07-calibrated ~3cyc/wave-inst) says the kernel is pure
// issue-rate-limited: cut static instructions. incs[] removed (round-12
// VGPR 36->56 regression); fallback recomputes inc exactly.
// Key = (run<<7)|(itc<<3)|gp: run 9 bits (sat add 128, entry clamp 511),
// itc 4 bits (16 its), gp 3 bits. Any run field >=480 -> exact scalar
// fallback (wave-uniform, ~never taken; worst-case exactness preserved).

#define TT 2048
#define CC 128
#define NW 64
#define NSEQ 512
#define SBITS_WORDS (NSEQ * NW)       // 128 KB
#define RES_WORDS (NSEQ * TT)         // 4 MB, layout [q][i]

typedef short          s16x2 __attribute__((ext_vector_type(2)));
typedef unsigned short u16x2 __attribute__((ext_vector_type(2)));

__device__ __forceinline__ unsigned pk_sign(unsigned x) {   // per-half sign mask
    s16x2 v = __builtin_bit_cast(s16x2, x);
    v = v >> 15;
    return __builtin_bit_cast(unsigned, v);
}
__device__ __forceinline__ unsigned pk_shl1(unsigned x) {
    u16x2 v = __builtin_bit_cast(u16x2, x);
    v = v << 1;
    return __builtin_bit_cast(unsigned, v);
}
__device__ __forceinline__ unsigned pk_addsat128(unsigned x) {
    u16x2 v = __builtin_bit_cast(u16x2, x);
    u16x2 c = {128, 128};
    v = __builtin_elementwise_add_sat(v, c);
    return __builtin_bit_cast(unsigned, v);
}
__device__ __forceinline__ unsigned pk_maxu(unsigned a, unsigned b) {
    u16x2 x = __builtin_bit_cast(u16x2, a);
    u16x2 y = __builtin_bit_cast(u16x2, b);
    u16x2 r = __builtin_elementwise_max(x, y);
    return __builtin_bit_cast(unsigned, r);
}

// ---------------- kernel 0: pack bits ----------------
__global__ void k_bits(const float* __restrict__ x, unsigned* __restrict__ sbits)
{
    const int b = blockIdx.x >> 6;
    const int w = blockIdx.x & 63;
    const int t = threadIdx.x;
    __shared__ unsigned char sbyt[32 * 132];

    #pragma unroll
    for (int r = 0; r < 16; ++r) {
        const int e  = t + (r << 8);
        const int ii = e >> 7;
        const int c  = e & 127;
        const float v = x[((size_t)(b * TT + (w << 5) + ii)) * CC + c];
        sbyt[ii * 132 + c] = (v > 0.0f) ? 1u : 0u;
    }
    __syncthreads();

    if (t < CC) {
        unsigned word = 0u;
        #pragma unroll
        for (int ii = 0; ii < 32; ++ii)
            word |= (unsigned)(sbyt[ii * 132 + t] & 1u) << ii;
        sbits[((b << 7) | t) * NW + w] = word;
    }
}

// ---------------- kernel 1: tiled diagonal DP (16 its / block) ----------------
// grid (20, 512): u -> (tile k, 512-diagonal chunk); triangular offsets
// {0,1,2,4,6,9,12,16}, counts ceil((k+1)/2). Over-range d masks itself
// (dw > wloc -> s < 0 -> em = 0).
__global__ __launch_bounds__(256, 4) void k_dp2(
    const unsigned* __restrict__ sbits, unsigned* __restrict__ res)
{
    const int u = blockIdx.x;            // 0..19
    const int q = blockIdx.y;            // sequence = b*128 + c
    int k = 0;
    if (u >= 1)  k = 1;
    if (u >= 2)  k = 2;
    if (u >= 4)  k = 3;
    if (u >= 6)  k = 4;
    if (u >= 9)  k = 5;
    if (u >= 12) k = 6;
    if (u >= 16) k = 7;
    const int OFFk = (k == 0) ? 0 : (k == 1) ? 1 : (k == 2) ? 2 : (k == 3) ? 4
                   : (k == 4) ? 6 : (k == 5) ? 9 : (k == 6) ? 12 : 16;
    const int chunk = u - OFFk;
    const int D0 = 1 + (chunk << 9);

    const int tid  = threadIdx.x;
    const int lane = tid & 63;
    const int wv   = tid >> 6;
    const int g    = lane >> 3;          // stream in wave
    const int lm   = lane & 7;           // lane within stream
    const int wB   = k << 3;
    const int wloc = wB + lm;            // fixed output word of this lane
    const int kb   = k << 8;

    __shared__ unsigned pad[128];        // [0..63]=0, [64+w]=word w
    __shared__ unsigned seedl[512];      // incoming run at tile base per diagonal
    __shared__ unsigned wres[4][8][33];

    if (tid < 64) pad[tid] = 0u;
    else if (tid < 128) pad[tid] = sbits[q * NW + (tid - 64)];
    __syncthreads();

    // --- seed precompute: thread t -> diagonals D0+t, D0+256+t ---
    #pragma unroll
    for (int e = 0; e < 2; ++e) {
        const int d = D0 + tid + (e << 8);
        unsigned acc = 0u;
        if (d < kb) {
            const int dw = d >> 5, dr = d & 31;
            for (int w = wB - 1; w >= 0; --w) {
                const int sw = w - dw;
                const unsigned u0 = pad[64 + sw];
                const unsigned u1 = pad[63 + sw];
                const unsigned shw = dr ? ((u0 << dr) | (u1 >> (32 - dr))) : u0;
                const unsigned ew = (sw > 0) ? 0xFFFFFFFFu
                                  : ((sw == 0) ? (0xFFFFFFFFu << dr) : 0u);
                const unsigned mw = (~(pad[64 + w] ^ shw)) & ew;
                const unsigned t2 = (mw == 0xFFFFFFFFu) ? 32u
                                  : (unsigned)__builtin_clz(~mw);
                acc += t2;
                if (t2 < 32u) break;
            }
        }
        seedl[tid + (e << 8)] = acc;
    }
    __syncthreads();

    const unsigned a = pad[64 + wloc];

    unsigned lmaxp[16];
    #pragma unroll
    for (int j = 0; j < 16; ++j) lmaxp[j] = 0u;

    #pragma unroll
    for (int it = 0; it < 16; ++it) {
        const int d  = D0 + (it << 5) + (wv << 3) + g;   // <= 2048 (masked)
        const int dw = d >> 5;
        const int dr = d & 31;                           // loop-invariant value

        const int s = wloc - dw;
        const unsigned b0 = pad[64 + s];
        const unsigned b1 = pad[63 + s];
        const unsigned sh = dr ? ((b0 << dr) | (b1 >> (32 - dr))) : b0;
        const unsigned em = (s > 0) ? 0xFFFFFFFFu
                          : ((s == 0) ? (0xFFFFFFFFu << dr) : 0u);
        const unsigned m = (~(a ^ sh)) & em;

        // --- incoming run: seed for stream heads, clz fast path otherwise ---
        const unsigned seedv = seedl[(it << 5) + (wv << 3) + g];
        const unsigned pm = (unsigned)__shfl_up((int)m, 1, 64);
        const unsigned lead = (unsigned)__builtin_clz(~pm | 1u);
        unsigned inc = (lm == 0) ? seedv : lead;

        // exact rare fallback: some lane's previous word fully matched
        if (__builtin_expect(
                __ballot((lm > 0) && (pm == 0xFFFFFFFFu)) != 0ULL, 0)) {
            if ((lm > 0) && (pm == 0xFFFFFFFFu)) {
                unsigned acc = 0u;
                int w;
                for (w = wloc - 1; w >= wB; --w) {
                    const int sw = w - dw;
                    const unsigned u0 = pad[64 + sw];
                    const unsigned u1 = pad[63 + sw];
                    const unsigned shw = dr ? ((u0 << dr) | (u1 >> (32 - dr))) : u0;
                    const unsigned ew = (sw > 0) ? 0xFFFFFFFFu
                                      : ((sw == 0) ? (0xFFFFFFFFu << dr) : 0u);
                    const unsigned mw = (~(pad[64 + w] ^ shw)) & ew;
                    const unsigned t2 = (mw == 0xFFFFFFFFu) ? 32u
                                      : (unsigned)__builtin_clz(~mw);
                    acc += t2;
                    if (t2 < 32u) break;
                }
                if (w < wB) acc += seedv;
                inc = acc;
            }
        }

        // --- chain-B (bits 16..31) entry: run into bit 16, capped clz ---
        const unsigned nm   = ~m;
        const unsigned u16c = (unsigned)__builtin_clz((nm << 16) | 0x8000u);
        const unsigned s16  = u16c + ((u16c == 16u) ? inc : 0u);

        const unsigned itcv = (unsigned)((15 - it) << 3) * 0x10001u;
        const unsigned ci = inc > 511u ? 511u : inc;
        const unsigned cs = s16 > 511u ? 511u : s16;
        unsigned rp = (ci << 7) | (cs << 23) | itcv;

        const unsigned mr  = __builtin_bitreverse32(m);
        unsigned mmr = (mr >> 16) | (mr << 16);

        #pragma unroll
        for (int j = 0; j < 16; ++j) {
            const unsigned sm = pk_sign(mmr);        // v_pk_ashrrev_i16
            mmr = pk_shl1(mmr);                      // v_pk_lshlrev_b16
            rp  = pk_addsat128(rp);                  // v_pk_add_u16 clamp
            rp  = (rp & sm) | (itcv & ~sm);          // v_bfi_b32
            lmaxp[j] = pk_maxu(lmaxp[j], rp);        // v_pk_max_u16
        }
    }

    // --- embed stream id into spare low bits ---
    const unsigned gk2 = (unsigned)(7 - g) * 0x10001u;
    #pragma unroll
    for (int j = 0; j < 16; ++j) lmaxp[j] |= gk2;

    // --- packed cross-stream reduce (lanes lm, lm+8, ..., lm+56) ---
    #pragma unroll
    for (int j = 0; j < 16; ++j) {
        unsigned v = lmaxp[j];
        v = pk_maxu(v, (unsigned)__shfl_xor((int)v, 8, 64));
        v = pk_maxu(v, (unsigned)__shfl_xor((int)v, 16, 64));
        v = pk_maxu(v, (unsigned)__shfl_xor((int)v, 32, 64));
        lmaxp[j] = v;
    }

    // --- clamp/saturation detect: any run field >= 480 ---
    unsigned mx = lmaxp[0];
    #pragma unroll
    for (int j = 1; j < 16; ++j) mx = pk_maxu(mx, lmaxp[j]);
    const bool ovf = ((mx & 0x0000F000u) == 0x0000F000u) ||
                     ((mx & 0xF0000000u) == 0xF0000000u);

    if (__builtin_expect(__ballot(ovf) == 0ULL, 1)) {
        // --- fast epilogue: expand 4 values per lane ---
        // dcode = Kw + (itc<<5) + gp, Kw = 2048 - D0 - (wv<<3) - 487
        const unsigned Kw = 1561u - (unsigned)D0 - (unsigned)(wv << 3);
        #pragma unroll
        for (int e = 0; e < 4; ++e) {
            const int j = ((g & 3) << 2) + e;
            const unsigned r32 = lmaxp[j];
            const unsigned h = (g >= 4) ? (r32 >> 16) : (r32 & 0xFFFFu);
            const unsigned v = ((h >> 7) << 11) + ((h & 0x78u) << 2) + (h & 7u) + Kw;
            wres[wv][lm][(g << 2) + e] = v;
        }
    } else {
        // --- exact fallback (rare, wave-uniform): full 32-bit recompute ---
        unsigned lm32[32];
        #pragma unroll
        for (int bb = 0; bb < 32; ++bb) lm32[bb] = 0u;
        for (int it = 0; it < 16; ++it) {
            const int d  = D0 + (it << 5) + (wv << 3) + g;
            const int dw = d >> 5;
            const int dr = d & 31;
            const unsigned dcode = (unsigned)(TT - d) & 2047u;
            const int s = wloc - dw;
            const unsigned b0 = pad[64 + s];
            const unsigned b1 = pad[63 + s];
            const unsigned sh = dr ? ((b0 << dr) | (b1 >> (32 - dr))) : b0;
            const unsigned em = (s > 0) ? 0xFFFFFFFFu
                              : ((s == 0) ? (0xFFFFFFFFu << dr) : 0u);
            const unsigned m = (~(a ^ sh)) & em;

            const unsigned seedv = seedl[(it << 5) + (wv << 3) + g];
            const unsigned pm = (unsigned)__shfl_up((int)m, 1, 64);
            unsigned inc;
            if (lm == 0) inc = seedv;
            else if (pm != 0xFFFFFFFFu) inc = (unsigned)__builtin_clz(~pm);
            else {
                unsigned acc = 0u;
                int w;
                for (w = wloc - 1; w >= wB; --w) {
                    const int sw = w - dw;
                    const unsigned u0 = pad[64 + sw];
                    const unsigned u1 = pad[63 + sw];
                    const unsigned shw = dr ? ((u0 << dr) | (u1 >> (32 - dr))) : u0;
                    const unsigned ew = (sw > 0) ? 0xFFFFFFFFu
                                      : ((sw == 0) ? (0xFFFFFFFFu << dr) : 0u);
                    const unsigned mw = (~(pad[64 + w] ^ shw)) & ew;
                    const unsigned t2 = (mw == 0xFFFFFFFFu) ? 32u
                                      : (unsigned)__builtin_clz(~mw);
                    acc += t2;
                    if (t2 < 32u) break;
                }
                if (w < wB) acc += seedv;
                inc = acc;
            }

            unsigned pkv = (inc << 11) | dcode;
            for (int bb = 0; bb < 32; ++bb) {
                pkv = ((m >> bb) & 1u) ? (pkv + 0x800u) : dcode;
                lm32[bb] = lm32[bb] >= pkv ? lm32[bb] : pkv;
            }
        }
        #pragma unroll
        for (int bb = 0; bb < 32; ++bb) {
            unsigned v = lm32[bb];
            v = max(v, (unsigned)__shfl_xor((int)v, 8, 64));
            v = max(v, (unsigned)__shfl_xor((int)v, 16, 64));
            v = max(v, (unsigned)__shfl_xor((int)v, 32, 64));
            lm32[bb] = v;
        }
        if (g == 0) {
            #pragma unroll
            for (int bb = 0; bb < 32; ++bb) wres[wv][lm][bb] = lm32[bb];
        }
    }
    __syncthreads();

    // --- block merge + contiguous atomics into res[q][i] ---
    {
        const int lw = tid >> 5, bb = tid & 31;
        const unsigned v = max(max(wres[0][lw][bb], wres[1][lw][bb]),
                               max(wres[2][lw][bb], wres[3][lw][bb]));
        if (v >> 11) {
            const int i = ((wB + lw) << 5) + bb;
            atomicMax(&res[(size_t)q * TT + i], v);
        }
    }
}

// ---------------- kernel 2: decode (LDS transpose) ----------------
__global__ void k_dec(const unsigned* __restrict__ sbits,
                      const unsigned* __restrict__ res,
                      const float* __restrict__ emb0,
                      const float* __restrict__ emb1,
                      float* __restrict__ out)
{
    const int b  = blockIdx.y;
    const int i0 = blockIdx.x << 4;
    const int t  = threadIdx.x;
    __shared__ float trans[16][CC + 4];

    const int c  = t >> 1;
    const int q8 = (t & 1) << 3;
    const unsigned* rp = res + ((size_t)((b << 7) | c) * TT) + i0 + q8;
    const unsigned* bw = sbits + ((size_t)((b << 7) | c)) * NW;
    const float e0 = emb0[c], e1 = emb1[c];

    #pragma unroll
    for (int jj = 0; jj < 8; ++jj) {
        const unsigned v = rp[jj];
        const int i = i0 + q8 + jj;
        float val = 0.0f;
        if (v >> 11) {
            const int d   = TT - (int)(v & 2047u);
            const int e1p = i - d + 1;
            val = ((bw[e1p >> 5] >> (e1p & 31)) & 1u) ? e1 : e0;
        }
        trans[q8 + jj][c] = val;
    }
    __syncthreads();

    const int ii = t >> 4;
    const int c0 = (t & 15) << 3;
    float4 w0 = *(const float4*)&trans[ii][c0];
    float4 w1 = *(const float4*)&trans[ii][c0 + 4];
    float* op = out + ((size_t)(b * TT + i0 + ii)) * CC + c0;
    *(float4*)op       = w0;
    *(float4*)(op + 4) = w1;
}

extern "C" void kernel_launch(void* const* d_in, const int* in_sizes, int n_in,
                              void* d_out, int out_size, void* d_ws, size_t ws_size,
                              hipStream_t stream)
{
    const float* x    = (const float*)d_in[0];
    const float* emb0 = (const float*)d_in[1];
    const float* emb1 = (const float*)d_in[2];
    float* out        = (float*)d_out;

    unsigned* sbits = (unsigned*)d_ws;                    // 128 KB
    unsigned* res   = (unsigned*)d_ws + SBITS_WORDS;      // 4 MB

    hipMemsetAsync((void*)res, 0, (size_t)RES_WORDS * 4, stream);
    k_bits<<<dim3(4 * 64), dim3(256), 0, stream>>>(x, sbits);
    k_dp2<<<dim3(20, NSEQ), dim3(256), 0, stream>>>(sbits, res);
    k_dec<<<dim3(TT / 16, 4), dim3(256), 0, stream>>>(sbits, res, emb0, emb1, out);
}